// Round 4
// baseline (152.682 us; speedup 1.0000x reference)
//
#include <hip/hip_runtime.h>

// QueryEncDec: 2 stacks x 128 layers of scalar GRU (H=in=1), T=256.
// Single-wave design: 64 lanes, lane j owns global layers 4j..4j+3.
// Step s: lane j advances timestep t = s - j through its 4 layers serially.
// Layer handoff lane j-1 -> j: DPP wave_shr:1 of committed h3 (register-only,
// lockstep, no sync). Lane-0 input feed: X preloaded into 4 VGPRs/lane,
// broadcast via v_readlane with uniform index. ZERO LDS ops, ZERO atomics,
// ZERO spins in the loop -- the only memory op is lane 63's output store.
// Gate constants (log2e, 2.0) folded into weights; commit-cndmasks are off
// the critical chain (candidate hc feeds the next cell directly).

#define T_LEN 256

typedef unsigned long long u64;

__device__ __forceinline__ float fexp2(float x) { return __builtin_amdgcn_exp2f(x); }
__device__ __forceinline__ float frcp(float x)  { return __builtin_amdgcn_rcpf(x); }

struct CellW {
    float wri, wrh, brc;   // r gate, pre-scaled by -log2(e)
    float wzi, wzh, bzc;   // z gate, pre-scaled by -log2(e)
    float wni, bni;        // n gate input half, pre-scaled by 2*log2(e)
    float wnh, bnh;        // n gate hidden half, pre-scaled by 2*log2(e)
};

// x -> h' serial chain: fma, exp2, add, rcp, fma, exp2, add, rcp, fma (~52 cy).
// All h-only terms (ghr/ghz/ghn/A/B inputs) parallelize off the chain.
__device__ __forceinline__ float cell_step(const CellW& c, float x, float h) {
    const float ghr = __builtin_fmaf(c.wrh, h, c.brc);
    const float ghz = __builtin_fmaf(c.wzh, h, c.bzc);
    const float ghn = __builtin_fmaf(c.wnh, h, c.bnh);
    const float gin = __builtin_fmaf(c.wni, x, c.bni);
    const float er  = fexp2(__builtin_fmaf(c.wri, x, ghr));
    const float ez  = fexp2(__builtin_fmaf(c.wzi, x, ghz));
    const float r   = frcp(1.0f + er);
    const float z   = frcp(1.0f + ez);
    const float en  = fexp2(__builtin_fmaf(r, ghn, gin));   // e^{2v}
    const float q   = frcp(1.0f + en);                      // n = 1-2q
    const float A   = __builtin_fmaf(z, h - 1.0f, 1.0f);
    const float B   = __builtin_fmaf(2.0f, z, -2.0f);
    return __builtin_fmaf(q, B, A);                         // (1-z)n + z h
}

__global__ __launch_bounds__(64, 1) void gru_lane4(
    const float* __restrict__ X,
    const float* __restrict__ enc_w_ih, const float* __restrict__ enc_w_hh,
    const float* __restrict__ enc_b_ih, const float* __restrict__ enc_b_hh,
    const float* __restrict__ dec_w_ih, const float* __restrict__ dec_w_hh,
    const float* __restrict__ dec_b_ih, const float* __restrict__ dec_b_hh,
    float* __restrict__ out)
{
    const int j = threadIdx.x;              // lane 0..63

    // preload X into registers: xr[m] holds X[64*m + j]
    const float xr0 = X[j];
    const float xr1 = X[64 + j];
    const float xr2 = X[128 + j];
    const float xr3 = X[192 + j];

    // per-lane params for 4 layers (torch gate order r,z,n), constants folded
    const float* wip = (j < 32) ? enc_w_ih : dec_w_ih;
    const float* whp = (j < 32) ? enc_w_hh : dec_w_hh;
    const float* bip = (j < 32) ? enc_b_ih : dec_b_ih;
    const float* bhp = (j < 32) ? enc_b_hh : dec_b_hh;
    const float L2E = 1.44269504088896340736f;

    CellW c[4];
    #pragma unroll
    for (int k = 0; k < 4; ++k) {
        const int pl = (4 * j + k) & 127;   // layer index within its stack
        c[k].wri = -L2E * wip[3 * pl + 0];
        c[k].wrh = -L2E * whp[3 * pl + 0];
        c[k].brc = -L2E * (bip[3 * pl + 0] + bhp[3 * pl + 0]);
        c[k].wzi = -L2E * wip[3 * pl + 1];
        c[k].wzh = -L2E * whp[3 * pl + 1];
        c[k].bzc = -L2E * (bip[3 * pl + 1] + bhp[3 * pl + 1]);
        c[k].wni = 2.0f * L2E * wip[3 * pl + 2];
        c[k].bni = 2.0f * L2E * bip[3 * pl + 2];
        c[k].wnh = 2.0f * L2E * whp[3 * pl + 2];
        c[k].bnh = 2.0f * L2E * bhp[3 * pl + 2];
    }

    float h0 = 0.0f, h1 = 0.0f, h2 = 0.0f, h3 = 0.0f;

    const int S = T_LEN + 63;               // 319 steps
    #pragma unroll 1
    for (int s = 0; s < S; ++s) {
        // layer handoff: lane j receives lane j-1's committed h3 (prev step)
        const int xb = __builtin_amdgcn_update_dpp(
            0, __builtin_bit_cast(int, h3), 0x138 /*wave_shr:1*/, 0xF, 0xF, false);
        float x = __builtin_bit_cast(float, xb);

        // lane-0 feed: X[s] via uniform-index readlane (no LDS)
        const int sel = s >> 6;             // uniform
        const int ln  = s & 63;             // uniform
        const int a0 = __builtin_amdgcn_readlane(__builtin_bit_cast(int, xr0), ln);
        const int a1 = __builtin_amdgcn_readlane(__builtin_bit_cast(int, xr1), ln);
        const int a2 = __builtin_amdgcn_readlane(__builtin_bit_cast(int, xr2), ln);
        const int a3 = __builtin_amdgcn_readlane(__builtin_bit_cast(int, xr3), ln);
        const int lo = (sel == 0) ? a0 : a1;        // uniform selects (SALU)
        const int hi = (sel == 2) ? a2 : a3;
        const float xv = __builtin_bit_cast(float, (sel < 2) ? lo : hi);
        x = (j == 0) ? xv : x;

        const int t = s - j;
        const bool act = (unsigned)t < (unsigned)T_LEN;

        // 4 serial cells; candidates feed forward unpredicated (equal to
        // committed values whenever act is true)
        const float hc0 = cell_step(c[0], x,   h0);
        const float hc1 = cell_step(c[1], hc0, h1);
        const float hc2 = cell_step(c[2], hc1, h2);
        const float hc3 = cell_step(c[3], hc2, h3);
        h0 = act ? hc0 : h0;
        h1 = act ? hc1 : h1;
        h2 = act ? hc2 : h2;
        h3 = act ? hc3 : h3;

        // dec_out[t]: layer 255 = lane 63's h3; s>=63 is a uniform branch
        if (s >= 63) {
            if (j == 63) out[s - 63] = h3;  // fire-and-forget store
        }
    }

    // dec_h: lanes 32..63 hold decoder layers 128..255; idx = 4j+k-128
    if (j >= 32) {
        const int base = T_LEN + 4 * j - 128;
        out[base + 0] = h0;
        out[base + 1] = h1;
        out[base + 2] = h2;
        out[base + 3] = h3;
    }
}

extern "C" void kernel_launch(void* const* d_in, const int* in_sizes, int n_in,
                              void* d_out, int out_size, void* d_ws, size_t ws_size,
                              hipStream_t stream) {
    const float* X        = (const float*)d_in[0];
    const float* enc_w_ih = (const float*)d_in[1];
    const float* enc_w_hh = (const float*)d_in[2];
    const float* enc_b_ih = (const float*)d_in[3];
    const float* enc_b_hh = (const float*)d_in[4];
    const float* dec_w_ih = (const float*)d_in[5];
    const float* dec_w_hh = (const float*)d_in[6];
    const float* dec_b_ih = (const float*)d_in[7];
    const float* dec_b_hh = (const float*)d_in[8];
    float* out = (float*)d_out;

    gru_lane4<<<1, 64, 0, stream>>>(X,
                                    enc_w_ih, enc_w_hh, enc_b_ih, enc_b_hh,
                                    dec_w_ih, dec_w_hh, dec_b_ih, dec_b_hh,
                                    out);
}

// Round 5
// 137.919 us; speedup vs baseline: 1.1070x; 1.1070x over previous
//
#include <hip/hip_runtime.h>

// QueryEncDec: 2 stacks x 128 layers of scalar GRU (H=in=1), T=256.
// 4 waves x 64 lanes; wave w lane j owns global layer 64w+j (1 layer/lane).
// Intra-wave handoff: DPP wave_shr:1 (register, lockstep, no sync).
// Cross-wave handoff: LDS mailbox, BATCHED -- every 16 steps one ds_read_b64
// per lane fetches 16 slots (lane j reads slot s0+(j&15)); one __ballot
// validates all 16 tags; per-step distribution is a literal-index v_readlane.
// Producer publishes every step with tag+value packed in one ds_write_b64
// (single-copy atomic; dump slots keep it branch-free). Wave 0's X feed uses
// the same path via a pre-tagged X mailbox => one code path for all waves.
// Natural inter-wave lag (64 steps) >> batch depth (16) => tag check passes
// on first try in steady state; spin only during pipeline fill.

#define T_LEN 256
#define MBOX  320              // 0..255 data slots, 256..319 per-lane dump
typedef unsigned long long u64;
typedef unsigned int u32;

__device__ __forceinline__ float fexp2(float x) { return __builtin_amdgcn_exp2f(x); }
__device__ __forceinline__ float frcp(float x)  { return __builtin_amdgcn_rcpf(x); }

struct CellW {
    float wri, wrh, brc;   // r gate, pre-scaled by -log2(e)
    float wzi, wzh, bzc;   // z gate, pre-scaled by -log2(e)
    float wni, bni;        // n gate input half, pre-scaled by 2*log2(e)
    float wnh, bnh;        // n gate hidden half, pre-scaled by 2*log2(e)
};

// x -> h' serial chain: fma,exp2,add,rcp,fma,exp2,add,rcp,fma (~56 cy).
// All h-only terms (ghr/ghz/ghn, A/B inputs) parallelize off the chain.
__device__ __forceinline__ float cell_step(const CellW& c, float x, float h) {
    const float ghr = __builtin_fmaf(c.wrh, h, c.brc);
    const float ghz = __builtin_fmaf(c.wzh, h, c.bzc);
    const float ghn = __builtin_fmaf(c.wnh, h, c.bnh);
    const float gin = __builtin_fmaf(c.wni, x, c.bni);
    const float er  = fexp2(__builtin_fmaf(c.wri, x, ghr));
    const float ez  = fexp2(__builtin_fmaf(c.wzi, x, ghz));
    const float r   = frcp(1.0f + er);
    const float z   = frcp(1.0f + ez);
    const float en  = fexp2(__builtin_fmaf(r, ghn, gin));   // e^{2v}
    const float q   = frcp(1.0f + en);                      // n = 1-2q
    const float A   = __builtin_fmaf(z, h - 1.0f, 1.0f);
    const float B   = __builtin_fmaf(2.0f, z, -2.0f);
    return __builtin_fmaf(q, B, A);                         // (1-z)n + z h
}

template<bool LAST>
__device__ __forceinline__ float run_wave(
    const int j, const CellW& c,
    volatile u64* inbox, volatile u64* outbox,
    float* __restrict__ out, float* __restrict__ dumpG)
{
    float h = 0.0f;
    u32 bval = 0;                       // this lane's batch value (slot s0+(j&15))
    const int js = j & 15;

    for (int s0 = 0; s0 < 320; s0 += 16) {
        if (s0 < T_LEN) {               // uniform branch; skip once inputs exhausted
            const int slot = s0 + js;
            u64 v = inbox[slot];        // one ds_read_b64 covers 16 future steps
            while (__ballot((u32)(v >> 32) == (u32)(slot + 1)) != ~0ull)
                v = inbox[slot];        // spin only during pipeline fill
            bval = (u32)v;
        }
        #pragma unroll
        for (int si = 0; si < 16; ++si) {
            const int s = s0 + si;
            // layer handoff: lane j <- lane j-1's committed h (prev step)
            const int hb = __builtin_amdgcn_update_dpp(
                0, __builtin_bit_cast(int, h), 0x138 /*wave_shr:1*/, 0xF, 0xF, false);
            // lane-0 feed: slot s = s0+si held by lane si (literal index)
            const u32 xv = (u32)__builtin_amdgcn_readlane((int)bval, si);
            const float x = (j == 0) ? __builtin_bit_cast(float, xv)
                                     : __builtin_bit_cast(float, hb);

            const float hc = cell_step(c, x, h);
            const int t = s - j;
            h = ((u32)t < (u32)T_LEN) ? hc : h;

            // publish lane 63's h for time tw (branch-free; dump slots for rest)
            const int tw = s - 63;                     // uniform
            const bool real = (j == 63) & (tw >= 0);
            const int widx = real ? tw : (T_LEN + j);  // dump: 256+j (write-only)
            outbox[widx] = ((u64)(u32)(tw + 1) << 32) |
                           (u64)__builtin_bit_cast(u32, h);

            if (LAST) {                                 // dec_out[tw] from lane 63
                const bool r3 = (j == 63) & (tw >= 0) & (s < 319);
                float* p = r3 ? (out + tw) : (dumpG + j);
                *p = h;                                 // fire-and-forget
            }
        }
    }
    return h;
}

__global__ __launch_bounds__(256, 1) void gru_pipe4(
    const float* __restrict__ X,
    const float* __restrict__ enc_w_ih, const float* __restrict__ enc_w_hh,
    const float* __restrict__ enc_b_ih, const float* __restrict__ enc_b_hh,
    const float* __restrict__ dec_w_ih, const float* __restrict__ dec_w_hh,
    const float* __restrict__ dec_b_ih, const float* __restrict__ dec_b_hh,
    float* __restrict__ out, float* __restrict__ dumpG)
{
    const int tid = threadIdx.x;        // global layer 0..255
    const int w   = tid >> 6;           // wave 0..3
    const int j   = tid & 63;

    __shared__ u64 xsM[T_LEN];          // X as a pre-tagged mailbox
    __shared__ u64 box[4][MBOX];        // box[3] = wave-3 trash (identical code path)

    xsM[tid] = ((u64)(u32)(tid + 1) << 32) |
               (u64)__builtin_bit_cast(u32, X[tid]);
    box[0][tid] = 0ull;                 // data slots 0..255 need tag=0
    box[1][tid] = 0ull;
    box[2][tid] = 0ull;

    // per-layer params (torch gate order r,z,n), constants folded
    const int pl = tid & 127;
    const float* wip = (tid < 128) ? enc_w_ih : dec_w_ih;
    const float* whp = (tid < 128) ? enc_w_hh : dec_w_hh;
    const float* bip = (tid < 128) ? enc_b_ih : dec_b_ih;
    const float* bhp = (tid < 128) ? enc_b_hh : dec_b_hh;
    const float L2E = 1.44269504088896340736f;
    CellW c;
    c.wri = -L2E * wip[3 * pl + 0];
    c.wrh = -L2E * whp[3 * pl + 0];
    c.brc = -L2E * (bip[3 * pl + 0] + bhp[3 * pl + 0]);
    c.wzi = -L2E * wip[3 * pl + 1];
    c.wzh = -L2E * whp[3 * pl + 1];
    c.bzc = -L2E * (bip[3 * pl + 1] + bhp[3 * pl + 1]);
    c.wni = 2.0f * L2E * wip[3 * pl + 2];
    c.bni = 2.0f * L2E * bip[3 * pl + 2];
    c.wnh = 2.0f * L2E * whp[3 * pl + 2];
    c.bnh = 2.0f * L2E * bhp[3 * pl + 2];

    __syncthreads();                    // the only block barrier

    volatile u64* inbox  = (w == 0) ? xsM : box[w - 1];
    volatile u64* outbox = box[w];

    float h;
    if (w == 3) h = run_wave<true >(j, c, inbox, outbox, out, dumpG);
    else        h = run_wave<false>(j, c, inbox, outbox, out, dumpG);

    // dec_h: final hidden of decoder layers (global layers 128..255)
    if (w >= 2) out[T_LEN + 64 * (w - 2) + j] = h;
}

extern "C" void kernel_launch(void* const* d_in, const int* in_sizes, int n_in,
                              void* d_out, int out_size, void* d_ws, size_t ws_size,
                              hipStream_t stream) {
    const float* X        = (const float*)d_in[0];
    const float* enc_w_ih = (const float*)d_in[1];
    const float* enc_w_hh = (const float*)d_in[2];
    const float* enc_b_ih = (const float*)d_in[3];
    const float* enc_b_hh = (const float*)d_in[4];
    const float* dec_w_ih = (const float*)d_in[5];
    const float* dec_w_hh = (const float*)d_in[6];
    const float* dec_b_ih = (const float*)d_in[7];
    const float* dec_b_hh = (const float*)d_in[8];
    float* out = (float*)d_out;
    float* dumpG = (float*)d_ws;

    gru_pipe4<<<1, 256, 0, stream>>>(X,
                                     enc_w_ih, enc_w_hh, enc_b_ih, enc_b_hh,
                                     dec_w_ih, dec_w_hh, dec_b_ih, dec_b_hh,
                                     out, dumpG);
}

// Round 7
// 112.572 us; speedup vs baseline: 1.3563x; 1.2252x over previous
//
#include <hip/hip_runtime.h>

// QueryEncDec: 2 stacks x 128 layers of scalar GRU (H=in=1), T=256.
// 4 waves x 64 lanes; wave w lane j owns global layer 64w+j.
// Intra-wave handoff: DPP wave_shr:1 (0x138; lane j <- lane j-1).
// Cross-wave handoff: LDS mailbox with BATCHED reads (1 ds_read_b64 / 16
// steps, validated by one __ballot) and BATCHED writes: lane-63 h history is
// collected via DPP wave_shl:1 (0x130; lane m <- lane m+1 -- history flows
// DOWN from the insertion point at lane 63). Every 16 steps lanes 48..63
// flush 16 tagged slots with ONE ds_write_b64. Consumers pre-spin once until
// the producer is ~94 steps ahead; steady-state tag checks then pass first
// try: zero per-step LDS ops, zero steady-state polls. Wave-3 output is
// likewise collector-batched (16-lane coalesced global store / 16 steps).
// R6 bug fixed here: collector used 0x138 (shr) so lanes 48..62 flushed
// zeros with valid tags; correct direction is 0x130 (shl).

#define T_LEN 256
#define MBOX  320              // 0..255 data slots, 256..319 per-lane dump
typedef unsigned long long u64;
typedef unsigned int u32;

__device__ __forceinline__ float fexp2(float x) { return __builtin_amdgcn_exp2f(x); }
__device__ __forceinline__ float frcp(float x)  { return __builtin_amdgcn_rcpf(x); }

struct CellW {
    float wri, wrh, brc;   // r gate, pre-scaled by -log2(e)
    float wzi, wzh, bzc;   // z gate, pre-scaled by -log2(e)
    float wni, bni;        // n gate input half, pre-scaled by 2*log2(e)
    float wnh, bnh;        // n gate hidden half, pre-scaled by 2*log2(e)
};

__device__ __forceinline__ float cell_step(const CellW& c, float x, float h) {
    const float ghr = __builtin_fmaf(c.wrh, h, c.brc);
    const float ghz = __builtin_fmaf(c.wzh, h, c.bzc);
    const float ghn = __builtin_fmaf(c.wnh, h, c.bnh);
    const float gin = __builtin_fmaf(c.wni, x, c.bni);
    const float er  = fexp2(__builtin_fmaf(c.wri, x, ghr));
    const float ez  = fexp2(__builtin_fmaf(c.wzi, x, ghz));
    const float r   = frcp(1.0f + er);
    const float z   = frcp(1.0f + ez);
    const float en  = fexp2(__builtin_fmaf(r, ghn, gin));   // e^{2v}
    const float q   = frcp(1.0f + en);                      // n = 1-2q
    const float A   = __builtin_fmaf(z, h - 1.0f, 1.0f);
    const float B   = __builtin_fmaf(2.0f, z, -2.0f);
    return __builtin_fmaf(q, B, A);                         // (1-z)n + z h
}

template<bool LAST>
__device__ __forceinline__ float run_wave(
    const int j, const CellW& c,
    volatile u64* inbox, volatile u64* outbox,
    float* __restrict__ out, float* __restrict__ dumpG)
{
    float h = 0.0f;
    u32 coll = 0;                       // collector: lane m holds lane-63 h(step s-(63-m))
    const int js = j & 15;

    // pre-spin: wait until producer has flushed slot 31 (its step ~94) ->
    // lag ~94 vs 78 needed; steady-state batch reads then always hit.
    // Wave 0's inbox is the pre-tagged X mailbox: passes immediately.
    {
        u64 v = inbox[31];
        while (__ballot((u32)(v >> 32) == 32u) != ~0ull) v = inbox[31];
    }

    for (int s0 = 0; s0 < 320; s0 += 16) {
        u32 bval = 0;
        if (s0 < T_LEN) {               // uniform; one ds_read_b64 per 16 steps
            const int slot = s0 + js;
            u64 v = inbox[slot];
            while (__ballot((u32)(v >> 32) == (u32)(slot + 1)) != ~0ull)
                v = inbox[slot];        // safety net; cold in steady state
            bval = (u32)v;
        }
        #pragma unroll
        for (int si = 0; si < 16; ++si) {
            const int s = s0 + si;
            // layer handoff: lane j <- lane j-1's committed h (prev step)
            const int hb = __builtin_amdgcn_update_dpp(
                0, __builtin_bit_cast(int, h), 0x138 /*wave_shr:1*/, 0xF, 0xF, false);
            // lane-0 feed: slot s held by batch-lane si (literal index)
            const u32 xv = (u32)__builtin_amdgcn_readlane((int)bval, si);
            const float x = (j == 0) ? __builtin_bit_cast(float, xv)
                                     : __builtin_bit_cast(float, hb);

            const float hc = cell_step(c, x, h);
            const int t = s - j;
            h = ((u32)t < (u32)T_LEN) ? hc : h;

            // collector: shift history DOWN (lane m <- lane m+1), insert at 63
            const int cs = __builtin_amdgcn_update_dpp(
                0, (int)coll, 0x130 /*wave_shl:1*/, 0xF, 0xF, false);
            coll = (j == 63) ? __builtin_bit_cast(u32, h) : (u32)cs;

            if (si == 14) {             // compile-time; flush at s = 16b+14
                // lane m in 48..63 holds lane-63 h for t = s + m - 126
                const int  tm   = s + j - 126;
                const bool real = (j >= 48) & (tm >= 0);
                const int  widx = real ? tm : (T_LEN + j);   // dump: 256+j
                outbox[widx] = ((u64)(u32)(tm + 1) << 32) | (u64)coll;
                if (LAST) {             // dec_out: coalesced 16-float store
                    float* p = real ? (out + tm) : (dumpG + j);
                    *p = __builtin_bit_cast(float, coll);
                }
            }
        }
    }
    return h;
}

__global__ __launch_bounds__(256, 1) void gru_pipe7(
    const float* __restrict__ X,
    const float* __restrict__ enc_w_ih, const float* __restrict__ enc_w_hh,
    const float* __restrict__ enc_b_ih, const float* __restrict__ enc_b_hh,
    const float* __restrict__ dec_w_ih, const float* __restrict__ dec_w_hh,
    const float* __restrict__ dec_b_ih, const float* __restrict__ dec_b_hh,
    float* __restrict__ out, float* __restrict__ dumpG)
{
    const int tid = threadIdx.x;        // global layer 0..255
    const int w   = tid >> 6;           // wave 0..3
    const int j   = tid & 63;

    __shared__ u64 xsM[T_LEN];          // X as a pre-tagged mailbox
    __shared__ u64 box[4][MBOX];        // box[3] = wave-3 trash (uniform code path)

    xsM[tid] = ((u64)(u32)(tid + 1) << 32) |
               (u64)__builtin_bit_cast(u32, X[tid]);
    box[0][tid] = 0ull;                 // data slots 0..255 need tag=0
    box[1][tid] = 0ull;
    box[2][tid] = 0ull;
    box[3][tid] = 0ull;

    // per-layer params (torch gate order r,z,n), constants folded
    const int pl = tid & 127;
    const float* wip = (tid < 128) ? enc_w_ih : dec_w_ih;
    const float* whp = (tid < 128) ? enc_w_hh : dec_w_hh;
    const float* bip = (tid < 128) ? enc_b_ih : dec_b_ih;
    const float* bhp = (tid < 128) ? enc_b_hh : dec_b_hh;
    const float L2E = 1.44269504088896340736f;
    CellW c;
    c.wri = -L2E * wip[3 * pl + 0];
    c.wrh = -L2E * whp[3 * pl + 0];
    c.brc = -L2E * (bip[3 * pl + 0] + bhp[3 * pl + 0]);
    c.wzi = -L2E * wip[3 * pl + 1];
    c.wzh = -L2E * whp[3 * pl + 1];
    c.bzc = -L2E * (bip[3 * pl + 1] + bhp[3 * pl + 1]);
    c.wni = 2.0f * L2E * wip[3 * pl + 2];
    c.bni = 2.0f * L2E * bip[3 * pl + 2];
    c.wnh = 2.0f * L2E * whp[3 * pl + 2];
    c.bnh = 2.0f * L2E * bhp[3 * pl + 2];

    __syncthreads();                    // the only block barrier

    volatile u64* inbox  = (w == 0) ? xsM : box[w - 1];
    volatile u64* outbox = box[w];

    float h;
    if (w == 3) h = run_wave<true >(j, c, inbox, outbox, out, dumpG);
    else        h = run_wave<false>(j, c, inbox, outbox, out, dumpG);

    // dec_h: final hidden of decoder layers (global layers 128..255)
    if (w >= 2) out[T_LEN + 64 * (w - 2) + j] = h;
}

extern "C" void kernel_launch(void* const* d_in, const int* in_sizes, int n_in,
                              void* d_out, int out_size, void* d_ws, size_t ws_size,
                              hipStream_t stream) {
    const float* X        = (const float*)d_in[0];
    const float* enc_w_ih = (const float*)d_in[1];
    const float* enc_w_hh = (const float*)d_in[2];
    const float* enc_b_ih = (const float*)d_in[3];
    const float* enc_b_hh = (const float*)d_in[4];
    const float* dec_w_ih = (const float*)d_in[5];
    const float* dec_w_hh = (const float*)d_in[6];
    const float* dec_b_ih = (const float*)d_in[7];
    const float* dec_b_hh = (const float*)d_in[8];
    float* out = (float*)d_out;
    float* dumpG = (float*)d_ws;

    gru_pipe7<<<1, 256, 0, stream>>>(X,
                                     enc_w_ih, enc_w_hh, enc_b_ih, enc_b_hh,
                                     dec_w_ih, dec_w_hh, dec_b_ih, dec_b_hh,
                                     out, dumpG);
}